// Round 3
// baseline (235.079 us; speedup 1.0000x reference)
//
#include <hip/hip_runtime.h>

// GCN layer: out = sum_r segment_sum(vals_r * inp[src_r], dst_r) @ W_r
// Round 7: fill is atomic-throughput-bound (53 us at 0.7% VALU, identical
// time at 51 MB and 26 MB writeback -> not BW-bound). Hide it: fuse fill
// blocks with GEMM blocks in ONE kernel (1:1 interleaved block ranges) so
// atomic stalls overlap MFMA compute. Also: fused converts, bin_cnt padded
// to one line/cell. Gather (LDS-CSR register acc) unchanged from round 6.
// N=50000, R=8, E=100000, IN=OUT=128.

constexpr int IN  = 128;
constexpr int OUT = 128;
constexpr int LDK = 136;   // padded LDS row (bf16 elems) = 272 B
constexpr int NPB = 64;    // nodes per bin (binning path)
constexpr int NPBLK = 16;  // nodes per agg block
constexpr int MAXE = 2048; // max entries one agg block can own (= NXCD*cap)
constexpr int NXCD = 8;
constexpr int CPAD = 16;   // ints per bin_cnt cell (64 B line padding)

typedef __attribute__((ext_vector_type(8))) short bf16x8;
typedef __attribute__((ext_vector_type(4))) float f32x4;

__device__ inline unsigned short f2bf(float f) {
    unsigned int u = __float_as_uint(f);
    u += 0x7fffu + ((u >> 16) & 1u);          // RNE
    return (unsigned short)(u >> 16);
}
__device__ inline float bflo(unsigned int u) { return __uint_as_float(u << 16); }
__device__ inline float bfhi(unsigned int u) { return __uint_as_float(u & 0xffff0000u); }

// ---------------- converts (separate, for fallback paths) -------------------
__global__ __launch_bounds__(256) void conv_inp_kernel(
    const float* __restrict__ x, unsigned short* __restrict__ y, int n8)
{
    const int i = blockIdx.x * 256 + threadIdx.x;
    if (i >= n8) return;
    const float4 a = ((const float4*)x)[i * 2];
    const float4 b = ((const float4*)x)[i * 2 + 1];
    uint4 o;
    o.x = (unsigned)f2bf(a.x) | ((unsigned)f2bf(a.y) << 16);
    o.y = (unsigned)f2bf(a.z) | ((unsigned)f2bf(a.w) << 16);
    o.z = (unsigned)f2bf(b.x) | ((unsigned)f2bf(b.y) << 16);
    o.w = (unsigned)f2bf(b.z) | ((unsigned)f2bf(b.w) << 16);
    ((uint4*)y)[i] = o;
}

__global__ __launch_bounds__(256) void conv_w_kernel(
    const float* __restrict__ w, unsigned short* __restrict__ wt, int total)
{
    const int t = blockIdx.x * 256 + threadIdx.x;
    if (t >= total) return;
    const int r = t >> 14, rem = t & 16383;
    const int n = rem >> 7, k = rem & 127;
    wt[t] = f2bf(w[(r << 14) + (k << 7) + n]);
}

// ---------------- fused converts (primary path) -----------------------------
__global__ __launch_bounds__(256) void conv_both_kernel(
    const float* __restrict__ x, unsigned short* __restrict__ y, int n8,
    const float* __restrict__ w, unsigned short* __restrict__ wt, int total,
    int nb_inp)
{
    if (blockIdx.x < nb_inp) {
        const int i = blockIdx.x * 256 + threadIdx.x;
        if (i >= n8) return;
        const float4 a = ((const float4*)x)[i * 2];
        const float4 b = ((const float4*)x)[i * 2 + 1];
        uint4 o;
        o.x = (unsigned)f2bf(a.x) | ((unsigned)f2bf(a.y) << 16);
        o.y = (unsigned)f2bf(a.z) | ((unsigned)f2bf(a.w) << 16);
        o.z = (unsigned)f2bf(b.x) | ((unsigned)f2bf(b.y) << 16);
        o.w = (unsigned)f2bf(b.z) | ((unsigned)f2bf(b.w) << 16);
        ((uint4*)y)[i] = o;
    } else {
        const int t = (blockIdx.x - nb_inp) * 256 + threadIdx.x;
        if (t >= total) return;
        const int r = t >> 14, rem = t & 16383;
        const int n = rem >> 7, k = rem & 127;
        wt[t] = f2bf(w[(r << 14) + (k << 7) + n]);
    }
}

// ---------------- fused GEMM + bin-fill -------------------------------------
// Even blocks: MFMA GEMM tile (compute-bound). Odd blocks: bin fill
// (atomic-latency-bound). Co-resident on every CU -> fill's atomic stalls
// hide under MFMA issue. Paths diverge at block granularity only.
__global__ __launch_bounds__(256) void gemm_fill_kernel(
    const unsigned short* __restrict__ inpb,
    const unsigned short* __restrict__ wt,
    unsigned short* __restrict__ h,
    const int* __restrict__ src, const int* __restrict__ dst,
    const float* __restrict__ vals, int* __restrict__ bin_cnt,
    int2* __restrict__ binned, int4* __restrict__ spill,
    int* __restrict__ spill_cnt,
    int n_nodes, int n_edges, int nbins, int cap, int spill_max,
    int gemm_gx, int fill_gx, int n_rel)
{
    __shared__ unsigned short As[128 * LDK];   // 34 KB (gemm path only)

    const int nG = gemm_gx * n_rel, nF = fill_gx * n_rel;
    const int bid = blockIdx.x;
    const int paired = 2 * (nG < nF ? nG : nF);
    bool is_fill; int idx;
    if (bid < paired) { is_fill = (bid & 1); idx = bid >> 1; }
    else { is_fill = (nF > nG); idx = (paired >> 1) + (bid - paired); }

    if (is_fill) {
        int xcd;
        asm volatile("s_getreg_b32 %0, hwreg(HW_REG_XCC_ID)" : "=s"(xcd));
        xcd &= (NXCD - 1);
        const int rel = idx / fill_gx, eblk = idx - rel * fill_gx;
        const int e = eblk * 256 + threadIdx.x;
        if (e >= n_edges) return;
        const size_t g = (size_t)rel * n_edges + e;
        const int d = dst[g];
        const int enc = rel * n_nodes + src[g];
        const int bin = d >> 6;                       // NPB = 64
        const int packed = ((d & 63) << 19) | enc;
        const int cell = xcd * nbins + bin;
        const int pos = atomicAdd(&bin_cnt[cell * CPAD], 1);
        if (pos < cap) {
            binned[(size_t)cell * cap + pos] =
                make_int2(packed, __float_as_int(vals[g]));
        } else {
            const int sp = atomicAdd(spill_cnt, 1);
            if (sp < spill_max)
                spill[sp] = make_int4(d, enc, __float_as_int(vals[g]), 0);
        }
        return;
    }

    // ---- GEMM path ----
    const int rel = idx / gemm_gx;
    const int row0 = (idx - rel * gemm_gx) * 128;
    const int tid = threadIdx.x;
    const int wave = tid >> 6, lane = tid & 63;
    const int m = lane & 15, q = lane >> 4;

    {
        const int r = tid >> 1;
        const int half = (tid & 1) * 64;
        const int grow = row0 + r;
        const uint4* gp = (const uint4*)(inpb + (size_t)grow * IN + half);
        uint4* lp = (uint4*)&As[r * LDK + half];
        #pragma unroll
        for (int i = 0; i < 8; ++i) {
            uint4 v = make_uint4(0u, 0u, 0u, 0u);
            if (grow < n_nodes) v = gp[i];
            lp[i] = v;
        }
    }

    bf16x8 bfrag[2][4];
    {
        const unsigned short* wtr = wt + ((size_t)rel * OUT + wave * 32) * IN;
        #pragma unroll
        for (int nt = 0; nt < 2; ++nt)
            #pragma unroll
            for (int ks = 0; ks < 4; ++ks)
                bfrag[nt][ks] = *(const bf16x8*)(
                    wtr + (size_t)(nt * 16 + m) * IN + ks * 32 + q * 8);
    }

    __syncthreads();

    f32x4 acc[8][2];
    #pragma unroll
    for (int mt = 0; mt < 8; ++mt)
        #pragma unroll
        for (int nt = 0; nt < 2; ++nt)
            acc[mt][nt] = (f32x4){0.f, 0.f, 0.f, 0.f};

    #pragma unroll
    for (int ks = 0; ks < 4; ++ks) {
        bf16x8 a[8];
        #pragma unroll
        for (int mt = 0; mt < 8; ++mt)
            a[mt] = *(const bf16x8*)&As[(mt * 16 + m) * LDK + ks * 32 + q * 8];
        #pragma unroll
        for (int mt = 0; mt < 8; ++mt) {
            acc[mt][0] = __builtin_amdgcn_mfma_f32_16x16x32_bf16(
                a[mt], bfrag[0][ks], acc[mt][0], 0, 0, 0);
            acc[mt][1] = __builtin_amdgcn_mfma_f32_16x16x32_bf16(
                a[mt], bfrag[1][ks], acc[mt][1], 0, 0, 0);
        }
    }

    unsigned short* hrel = h + (size_t)rel * n_nodes * OUT;
    #pragma unroll
    for (int mt = 0; mt < 8; ++mt) {
        #pragma unroll
        for (int rg = 0; rg < 4; ++rg) {
            const int row = row0 + mt * 16 + q * 4 + rg;
            if (row < n_nodes) {
                unsigned short* hp = hrel + (size_t)row * OUT + wave * 32 + m;
                hp[0]  = f2bf(acc[mt][0][rg]);
                hp[16] = f2bf(acc[mt][1][rg]);
            }
        }
    }
}

// ---------------- standalone MFMA GEMM (fallback paths) ---------------------
__global__ __launch_bounds__(256) void mfma_gemm(
    const unsigned short* __restrict__ inpb,
    const unsigned short* __restrict__ wt,
    unsigned short* __restrict__ h, int rel_base, int n_nodes)
{
    __shared__ unsigned short As[128 * LDK];   // 34 KB

    const int rel = rel_base + blockIdx.y;
    const int row0 = blockIdx.x * 128;
    const int tid = threadIdx.x;
    const int wave = tid >> 6, lane = tid & 63;
    const int m = lane & 15, q = lane >> 4;

    {
        const int r = tid >> 1;
        const int half = (tid & 1) * 64;
        const int grow = row0 + r;
        const uint4* gp = (const uint4*)(inpb + (size_t)grow * IN + half);
        uint4* lp = (uint4*)&As[r * LDK + half];
        #pragma unroll
        for (int i = 0; i < 8; ++i) {
            uint4 v = make_uint4(0u, 0u, 0u, 0u);
            if (grow < n_nodes) v = gp[i];
            lp[i] = v;
        }
    }

    bf16x8 bfrag[2][4];
    {
        const unsigned short* wtr = wt + ((size_t)rel * OUT + wave * 32) * IN;
        #pragma unroll
        for (int nt = 0; nt < 2; ++nt)
            #pragma unroll
            for (int ks = 0; ks < 4; ++ks)
                bfrag[nt][ks] = *(const bf16x8*)(
                    wtr + (size_t)(nt * 16 + m) * IN + ks * 32 + q * 8);
    }

    __syncthreads();

    f32x4 acc[8][2];
    #pragma unroll
    for (int mt = 0; mt < 8; ++mt)
        #pragma unroll
        for (int nt = 0; nt < 2; ++nt)
            acc[mt][nt] = (f32x4){0.f, 0.f, 0.f, 0.f};

    #pragma unroll
    for (int ks = 0; ks < 4; ++ks) {
        bf16x8 a[8];
        #pragma unroll
        for (int mt = 0; mt < 8; ++mt)
            a[mt] = *(const bf16x8*)&As[(mt * 16 + m) * LDK + ks * 32 + q * 8];
        #pragma unroll
        for (int mt = 0; mt < 8; ++mt) {
            acc[mt][0] = __builtin_amdgcn_mfma_f32_16x16x32_bf16(
                a[mt], bfrag[0][ks], acc[mt][0], 0, 0, 0);
            acc[mt][1] = __builtin_amdgcn_mfma_f32_16x16x32_bf16(
                a[mt], bfrag[1][ks], acc[mt][1], 0, 0, 0);
        }
    }

    unsigned short* hrel = h + (size_t)blockIdx.y * n_nodes * OUT;
    #pragma unroll
    for (int mt = 0; mt < 8; ++mt) {
        #pragma unroll
        for (int rg = 0; rg < 4; ++rg) {
            const int row = row0 + mt * 16 + q * 4 + rg;
            if (row < n_nodes) {
                unsigned short* hp = hrel + (size_t)row * OUT + wave * 32 + m;
                hp[0]  = f2bf(acc[mt][0][rg]);
                hp[16] = f2bf(acc[mt][1][rg]);
            }
        }
    }
}

// ---------------- bin aggregate v2: LDS-CSR + register gather ---------------
__global__ __launch_bounds__(256) void bin_agg2_kernel(
    const unsigned short* __restrict__ h, const int2* __restrict__ binned,
    const int* __restrict__ bin_cnt, float* __restrict__ out,
    int n_nodes, int nbins, int cap)
{
    __shared__ int2 sorted[MAXE];               // 16 KB
    __shared__ int lcnt[NPBLK], loff[NPBLK], lcur[NPBLK];
    __shared__ int cellcnt[NXCD];

    const int bin = blockIdx.x >> 2;
    const int nlo = (blockIdx.x & 3) * NPBLK;   // local node base within bin
    const int tid = threadIdx.x;

    if (tid < NPBLK) lcnt[tid] = 0;
    if (tid >= 32 && tid < 32 + NXCD) {
        int c = bin_cnt[((tid - 32) * nbins + bin) * CPAD];
        cellcnt[tid - 32] = c > cap ? cap : c;
    }
    __syncthreads();

    // pass 1: count entries per local node
    for (int xc = 0; xc < NXCD; ++xc) {
        const int cnt = cellcnt[xc];
        const int2* __restrict__ b = binned + (size_t)(xc * nbins + bin) * cap;
        for (int i = tid; i < cnt; i += 256) {
            const int ln = ((b[i].x >> 19) & 63) - nlo;
            if ((unsigned)ln < (unsigned)NPBLK) atomicAdd(&lcnt[ln], 1);
        }
    }
    __syncthreads();
    if (tid == 0) {
        int s = 0;
        #pragma unroll
        for (int i = 0; i < NPBLK; ++i) { loff[i] = s; s += lcnt[i]; }
    }
    if (tid < NPBLK) lcur[tid] = 0;
    __syncthreads();

    // pass 2: place entries (cells are L2-hot after pass 1)
    for (int xc = 0; xc < NXCD; ++xc) {
        const int cnt = cellcnt[xc];
        const int2* __restrict__ b = binned + (size_t)(xc * nbins + bin) * cap;
        for (int i = tid; i < cnt; i += 256) {
            const int2 e = b[i];
            const int ln = ((e.x >> 19) & 63) - nlo;
            if ((unsigned)ln < (unsigned)NPBLK) {
                const int pos = atomicAdd(&lcur[ln], 1);
                sorted[loff[ln] + pos] = e;
            }
        }
    }
    __syncthreads();

    // gather: half-wave hw handles local nodes 2*hw, 2*hw+1
    const int hw = tid >> 5, lane = tid & 31;
    #pragma unroll
    for (int k = 0; k < 2; ++k) {
        const int ln = hw * 2 + k;
        const int node = bin * NPB + nlo + ln;
        if (node >= n_nodes) continue;
        const int base = loff[ln];
        const int cnt  = lcnt[ln];
        float4 acc = make_float4(0.f, 0.f, 0.f, 0.f);
        int j = 0;
        for (; j + 4 <= cnt; j += 4) {
            const int2 r0 = sorted[base + j],     r1 = sorted[base + j + 1];
            const int2 r2 = sorted[base + j + 2], r3 = sorted[base + j + 3];
            const uint2 h0 = ((const uint2*)(h + (size_t)(r0.x & 0x7ffff) * OUT))[lane];
            const uint2 h1 = ((const uint2*)(h + (size_t)(r1.x & 0x7ffff) * OUT))[lane];
            const uint2 h2 = ((const uint2*)(h + (size_t)(r2.x & 0x7ffff) * OUT))[lane];
            const uint2 h3 = ((const uint2*)(h + (size_t)(r3.x & 0x7ffff) * OUT))[lane];
            const float v0 = __int_as_float(r0.y), v1 = __int_as_float(r1.y);
            const float v2 = __int_as_float(r2.y), v3 = __int_as_float(r3.y);
            acc.x += v0*bflo(h0.x) + v1*bflo(h1.x) + v2*bflo(h2.x) + v3*bflo(h3.x);
            acc.y += v0*bfhi(h0.x) + v1*bfhi(h1.x) + v2*bfhi(h2.x) + v3*bfhi(h3.x);
            acc.z += v0*bflo(h0.y) + v1*bflo(h1.y) + v2*bflo(h2.y) + v3*bflo(h3.y);
            acc.w += v0*bfhi(h0.y) + v1*bfhi(h1.y) + v2*bfhi(h2.y) + v3*bfhi(h3.y);
        }
        for (; j < cnt; ++j) {
            const int2 r0 = sorted[base + j];
            const float v = __int_as_float(r0.y);
            const uint2 hv = ((const uint2*)(h + (size_t)(r0.x & 0x7ffff) * OUT))[lane];
            acc.x += v * bflo(hv.x); acc.y += v * bfhi(hv.x);
            acc.z += v * bflo(hv.y); acc.w += v * bfhi(hv.y);
        }
        ((float4*)(out + (size_t)node * OUT))[lane] = acc;
    }
}

// ---------------- legacy bucket fill (fallback paths) -----------------------
__global__ __launch_bounds__(256) void fill_kernel(
    const int* __restrict__ src, const int* __restrict__ dst,
    const float* __restrict__ vals, int* __restrict__ counts,
    int2* __restrict__ bucket, int4* __restrict__ spill,
    int* __restrict__ spill_cnt, int n_edges, int n_nodes,
    int cap, int spill_max)
{
    const int e = blockIdx.x * 256 + threadIdx.x;
    if (e >= n_edges) return;
    const size_t g = (size_t)blockIdx.y * n_edges + e;
    const int d = dst[g];
    const int enc = blockIdx.y * n_nodes + src[g];   // h row index
    const int pos = atomicAdd(&counts[d], 1);
    if (pos < cap) {
        bucket[(size_t)d * cap + pos] = make_int2(enc, __float_as_int(vals[g]));
    } else {
        const int sp = atomicAdd(spill_cnt, 1);
        if (sp < spill_max)
            spill[sp] = make_int4(d, enc, __float_as_int(vals[g]), 0);
    }
}

// ---------------- legacy gather (fallback paths) ----------------------------
__global__ __launch_bounds__(256) void gather_kernel(
    const unsigned short* __restrict__ h, const int2* __restrict__ bucket,
    const int* __restrict__ counts, float* __restrict__ out,
    int n_nodes, int cap, int accum)
{
    const int node = blockIdx.x * 8 + (threadIdx.x >> 5);
    const int lane = threadIdx.x & 31;
    if (node >= n_nodes) return;
    int cnt = counts[node];
    if (cnt > cap) cnt = cap;
    const int2* __restrict__ b = bucket + (size_t)node * cap;
    float4* __restrict__ op = (float4*)(out + (size_t)node * OUT);

    float4 acc = accum ? op[lane] : make_float4(0.f, 0.f, 0.f, 0.f);
    int j = 0;
    for (; j + 4 <= cnt; j += 4) {
        const int2 r0 = b[j], r1 = b[j + 1], r2 = b[j + 2], r3 = b[j + 3];
        const uint2 h0 = ((const uint2*)(h + (size_t)r0.x * OUT))[lane];
        const uint2 h1 = ((const uint2*)(h + (size_t)r1.x * OUT))[lane];
        const uint2 h2 = ((const uint2*)(h + (size_t)r2.x * OUT))[lane];
        const uint2 h3 = ((const uint2*)(h + (size_t)r3.x * OUT))[lane];
        const float v0 = __int_as_float(r0.y), v1 = __int_as_float(r1.y);
        const float v2 = __int_as_float(r2.y), v3 = __int_as_float(r3.y);
        acc.x += v0*bflo(h0.x) + v1*bflo(h1.x) + v2*bflo(h2.x) + v3*bflo(h3.x);
        acc.y += v0*bfhi(h0.x) + v1*bfhi(h1.x) + v2*bfhi(h2.x) + v3*bfhi(h3.x);
        acc.z += v0*bflo(h0.y) + v1*bflo(h1.y) + v2*bflo(h2.y) + v3*bflo(h3.y);
        acc.w += v0*bfhi(h0.y) + v1*bfhi(h1.y) + v2*bfhi(h2.y) + v3*bfhi(h3.y);
    }
    for (; j < cnt; ++j) {
        const int2 r0 = b[j];
        const float v = __int_as_float(r0.y);
        const uint2 hv = ((const uint2*)(h + (size_t)r0.x * OUT))[lane];
        acc.x += v * bflo(hv.x); acc.y += v * bfhi(hv.x);
        acc.z += v * bflo(hv.y); acc.w += v * bfhi(hv.y);
    }
    op[lane] = acc;
}

// ---------------- spill cleanup (expected ~0 edges) -------------------------
__global__ __launch_bounds__(256) void spill_kernel(
    const unsigned short* __restrict__ h, const int4* __restrict__ spill,
    const int* __restrict__ spill_cnt, float* __restrict__ out, int spill_max)
{
    int n = *spill_cnt;
    if (n > spill_max) n = spill_max;
    const int w = (blockIdx.x * 256 + threadIdx.x) >> 6;
    const int lane = threadIdx.x & 63;
    const int nw = gridDim.x * 4;
    for (int i = w; i < n; i += nw) {
        const int4 s = spill[i];
        const float v = __int_as_float(s.z);
        const unsigned int u = ((const unsigned int*)(h + (size_t)s.y * OUT))[lane];
        float* __restrict__ orow = out + (size_t)s.x * OUT;
        __hip_atomic_fetch_add(orow + lane * 2,     v * bflo(u),
                               __ATOMIC_RELAXED, __HIP_MEMORY_SCOPE_AGENT);
        __hip_atomic_fetch_add(orow + lane * 2 + 1, v * bfhi(u),
                               __ATOMIC_RELAXED, __HIP_MEMORY_SCOPE_AGENT);
    }
}

// ---------------- last-resort scatter (atomic, bf16 h, per relation) --------
__global__ __launch_bounds__(256) void scatter_kernel(
    const unsigned short* __restrict__ h, const int* __restrict__ src,
    const int* __restrict__ dst, const float* __restrict__ vals,
    float* __restrict__ out, int n_edges)
{
    const int e = blockIdx.x * 8 + (threadIdx.x >> 5);
    if (e >= n_edges) return;
    const int lane = threadIdx.x & 31;
    const int s = src[e];
    const int d = dst[e];
    const float v = vals[e];
    const unsigned int* __restrict__ hrow =
        (const unsigned int*)(h + (size_t)s * OUT);
    float* __restrict__ orow = out + (size_t)d * OUT;
    #pragma unroll
    for (int kk = 0; kk < 2; ++kk) {
        const int jj = lane + kk * 32;      // uint index: cols 2jj, 2jj+1
        const unsigned int u = hrow[jj];
        __hip_atomic_fetch_add(orow + jj * 2,     v * bflo(u),
                               __ATOMIC_RELAXED, __HIP_MEMORY_SCOPE_AGENT);
        __hip_atomic_fetch_add(orow + jj * 2 + 1, v * bfhi(u),
                               __ATOMIC_RELAXED, __HIP_MEMORY_SCOPE_AGENT);
    }
}

extern "C" void kernel_launch(void* const* d_in, const int* in_sizes, int n_in,
                              void* d_out, int out_size, void* d_ws, size_t ws_size,
                              hipStream_t stream) {
    const float* inp     = (const float*)d_in[0];
    const int*   src     = (const int*)  d_in[1];
    const int*   dst     = (const int*)  d_in[2];
    const float* vals    = (const float*)d_in[3];
    const float* weights = (const float*)d_in[4];
    float* out = (float*)d_out;

    const int n_nodes = in_sizes[0] / IN;            // 50000
    const int n_rel   = in_sizes[4] / (IN * OUT);    // 8
    const int n_edges = in_sizes[1] / n_rel;         // 100000

    auto align_up = [](size_t x) { return (x + 255) & ~(size_t)255; };
    const int SPILL_MAX = 65536;
    const size_t sz_inpb   = align_up((size_t)n_nodes * IN * 2);
    const size_t sz_wt     = align_up((size_t)n_rel * IN * OUT * 2);
    const size_t sz_spill  = align_up((size_t)SPILL_MAX * 16);

    const int conv_n8 = n_nodes * IN / 8;
    const int wt_tot  = n_rel * IN * OUT;
    const int gemm_gx = (n_nodes + 127) / 128;
    const int gath_gx = (n_nodes + 7) / 8;
    const int fill_gx = (n_edges + 255) / 256;
    const int nbins   = (n_nodes + NPB - 1) / NPB;

    // ---- primary path: fused gemm||fill + LDS-CSR register gather ----
    if ((size_t)n_rel * n_nodes < (1u << 19)) {
        const size_t sz_h    = (size_t)n_rel * n_nodes * OUT * 2;
        const size_t sz_bcnt = align_up(((size_t)NXCD * nbins * CPAD + CPAD) * 4);
        int cap = 0;
        const int caps[] = {256, 192};
        for (int c : caps) {
            const size_t sz_binned =
                align_up((size_t)NXCD * nbins * c * 8);
            if (sz_inpb + sz_wt + sz_bcnt + sz_spill + sz_h + sz_binned
                <= ws_size) { cap = c; break; }
        }
        if (cap > 0) {
            const size_t sz_binned = align_up((size_t)NXCD * nbins * cap * 8);
            char* p = (char*)d_ws;
            unsigned short* inpb = (unsigned short*)p;  p += sz_inpb;
            unsigned short* wtb  = (unsigned short*)p;  p += sz_wt;
            int*   bin_cnt = (int*)p;   p += sz_bcnt;
            int4*  spill   = (int4*)p;  p += sz_spill;
            unsigned short* h = (unsigned short*)p;     p += sz_h;
            int2*  binned  = (int2*)p;  p += sz_binned;
            int*   spill_cnt = bin_cnt + (size_t)NXCD * nbins * CPAD;

            const int nb_inp = (conv_n8 + 255) / 256;
            const int nb_w   = (wt_tot + 255) / 256;
            conv_both_kernel<<<nb_inp + nb_w, 256, 0, stream>>>(
                inp, inpb, conv_n8, weights, wtb, wt_tot, nb_inp);
            hipMemsetAsync(bin_cnt, 0,
                           ((size_t)NXCD * nbins * CPAD + CPAD) * 4, stream);
            const int nG = gemm_gx * n_rel, nF = fill_gx * n_rel;
            gemm_fill_kernel<<<nG + nF, 256, 0, stream>>>(
                inpb, wtb, h, src, dst, vals, bin_cnt, binned, spill,
                spill_cnt, n_nodes, n_edges, nbins, cap, SPILL_MAX,
                gemm_gx, fill_gx, n_rel);
            bin_agg2_kernel<<<nbins * (NPB / NPBLK), 256, 0, stream>>>(
                h, binned, bin_cnt, out, n_nodes, nbins, cap);
            spill_kernel<<<128, 256, 0, stream>>>(h, spill, spill_cnt, out,
                                                  SPILL_MAX);
            return;
        }
    }

    const size_t sz_counts = align_up((size_t)(n_nodes + 1) * 4);
    const size_t fixed = sz_inpb + sz_wt + sz_counts + sz_spill;

    // ---- legacy full path: per-node buckets, all relations at once ----
    {
        const size_t sz_h = (size_t)n_rel * n_nodes * OUT * 2;
        int cap = 0;
        const int caps[] = {64, 48, 32, 24, 20};
        for (int c : caps) {
            if (fixed + sz_h + align_up((size_t)n_nodes * c * 8) <= ws_size) {
                cap = c; break;
            }
        }
        if (cap > 0) {
            char* p = (char*)d_ws;
            unsigned short* inpb = (unsigned short*)p;  p += sz_inpb;
            unsigned short* wtb  = (unsigned short*)p;  p += sz_wt;
            int*   counts = (int*)p;    p += sz_counts;
            int4*  spill  = (int4*)p;   p += sz_spill;
            unsigned short* h = (unsigned short*)p;     p += sz_h;
            int2*  bucket = (int2*)p;
            int*   spill_cnt = counts + n_nodes;

            conv_inp_kernel<<<(conv_n8 + 255) / 256, 256, 0, stream>>>(
                inp, inpb, conv_n8);
            conv_w_kernel<<<(wt_tot + 255) / 256, 256, 0, stream>>>(
                weights, wtb, wt_tot);
            hipMemsetAsync(counts, 0, (size_t)(n_nodes + 1) * 4, stream);
            dim3 fg(fill_gx, n_rel);
            fill_kernel<<<fg, 256, 0, stream>>>(src, dst, vals, counts, bucket,
                                                spill, spill_cnt, n_edges,
                                                n_nodes, cap, SPILL_MAX);
            dim3 gg(gemm_gx, n_rel);
            mfma_gemm<<<gg, 256, 0, stream>>>(inpb, wtb, h, 0, n_nodes);
            gather_kernel<<<gath_gx, 256, 0, stream>>>(h, bucket, counts, out,
                                                       n_nodes, cap, 0);
            spill_kernel<<<128, 256, 0, stream>>>(h, spill, spill_cnt, out,
                                                  SPILL_MAX);
            return;
        }
    }

    // ---- per-relation path ----
    {
        const size_t sz_h = (size_t)n_nodes * OUT * 2;
        int cap = 0;
        const int caps[] = {16, 12, 8};
        for (int c : caps) {
            if (fixed + sz_h + align_up((size_t)n_nodes * c * 8) <= ws_size) {
                cap = c; break;
            }
        }
        if (cap > 0) {
            char* p = (char*)d_ws;
            unsigned short* inpb = (unsigned short*)p;  p += sz_inpb;
            unsigned short* wtb  = (unsigned short*)p;  p += sz_wt;
            int*   counts = (int*)p;    p += sz_counts;
            int4*  spill  = (int4*)p;   p += sz_spill;
            unsigned short* h = (unsigned short*)p;     p += sz_h;
            int2*  bucket = (int2*)p;
            int*   spill_cnt = counts + n_nodes;

            conv_inp_kernel<<<(conv_n8 + 255) / 256, 256, 0, stream>>>(
                inp, inpb, conv_n8);
            conv_w_kernel<<<(wt_tot + 255) / 256, 256, 0, stream>>>(
                weights, wtb, wt_tot);
            for (int r = 0; r < n_rel; ++r) {
                const size_t eoff = (size_t)r * n_edges;
                hipMemsetAsync(counts, 0, (size_t)(n_nodes + 1) * 4, stream);
                dim3 fg(fill_gx, 1);
                fill_kernel<<<fg, 256, 0, stream>>>(src + eoff, dst + eoff,
                                                    vals + eoff, counts, bucket,
                                                    spill, spill_cnt, n_edges,
                                                    n_nodes, cap, SPILL_MAX);
                dim3 gg(gemm_gx, 1);
                mfma_gemm<<<gg, 256, 0, stream>>>(inpb, wtb, h, r, n_nodes);
                gather_kernel<<<gath_gx, 256, 0, stream>>>(h, bucket, counts,
                                                           out, n_nodes, cap,
                                                           r > 0 ? 1 : 0);
                spill_kernel<<<128, 256, 0, stream>>>(h, spill, spill_cnt, out,
                                                      SPILL_MAX);
            }
            return;
        }
    }

    // ---- last resort: per-relation gemm + atomic scatter ----
    {
        char* p = (char*)d_ws;
        unsigned short* inpb = (unsigned short*)p;  p += sz_inpb;
        unsigned short* wtb  = (unsigned short*)p;  p += sz_wt;
        unsigned short* h = (unsigned short*)p;

        conv_inp_kernel<<<(conv_n8 + 255) / 256, 256, 0, stream>>>(
            inp, inpb, conv_n8);
        conv_w_kernel<<<(wt_tot + 255) / 256, 256, 0, stream>>>(
            weights, wtb, wt_tot);
        hipMemsetAsync(out, 0, (size_t)n_nodes * OUT * 4, stream);
        const int sgx = (n_edges + 7) / 8;
        for (int r = 0; r < n_rel; ++r) {
            const size_t eoff = (size_t)r * n_edges;
            dim3 gg(gemm_gx, 1);
            mfma_gemm<<<gg, 256, 0, stream>>>(inpb, wtb, h, r, n_nodes);
            scatter_kernel<<<sgx, 256, 0, stream>>>(h, src + eoff, dst + eoff,
                                                    vals + eoff, out, n_edges);
        }
    }
}

// Round 4
// 221.605 us; speedup vs baseline: 1.0608x; 1.0608x over previous
//
#include <hip/hip_runtime.h>

// GCN layer: out = sum_r segment_sum(vals_r * inp[src_r], dst_r) @ W_r
// Round 8: commute the einsum — segment-sum in INPUT space, then fused
// per-bin MFMA against W_r. Kills the h intermediate entirely (was 102 MB
// write + 205 MB random read from a >L2 table). Random gather now hits the
// L2-resident 12.8 MB inp table. Pipeline: memset -> prep (convert||fill,
// conv hidden under atomic-bound fill) -> bin_gather_gemm -> spill_w.
// N=50000, R=8, E=100000, IN=OUT=128.

constexpr int IN  = 128;
constexpr int OUT = 128;
constexpr int LDK = 136;   // padded LDS row (bf16 elems) = 272 B
constexpr int NPB = 64;    // nodes per bin
constexpr int NGRP = 512;  // 8 rel * 64 nodes per bin
constexpr int MAXE = 2048; // sorted capacity = NXCD * max cap
constexpr int NXCD = 8;
constexpr int CPAD = 16;   // ints per bin_cnt cell (64 B line padding)

typedef __attribute__((ext_vector_type(8))) short bf16x8;
typedef __attribute__((ext_vector_type(4))) float f32x4;

__device__ inline unsigned short f2bf(float f) {
    unsigned int u = __float_as_uint(f);
    u += 0x7fffu + ((u >> 16) & 1u);          // RNE
    return (unsigned short)(u >> 16);
}
__device__ inline float bflo(unsigned int u) { return __uint_as_float(u << 16); }
__device__ inline float bfhi(unsigned int u) { return __uint_as_float(u & 0xffff0000u); }

// ---------------- converts (standalone, fallback paths) ---------------------
__global__ __launch_bounds__(256) void conv_inp_kernel(
    const float* __restrict__ x, unsigned short* __restrict__ y, int n8)
{
    const int i = blockIdx.x * 256 + threadIdx.x;
    if (i >= n8) return;
    const float4 a = ((const float4*)x)[i * 2];
    const float4 b = ((const float4*)x)[i * 2 + 1];
    uint4 o;
    o.x = (unsigned)f2bf(a.x) | ((unsigned)f2bf(a.y) << 16);
    o.y = (unsigned)f2bf(a.z) | ((unsigned)f2bf(a.w) << 16);
    o.z = (unsigned)f2bf(b.x) | ((unsigned)f2bf(b.y) << 16);
    o.w = (unsigned)f2bf(b.z) | ((unsigned)f2bf(b.w) << 16);
    ((uint4*)y)[i] = o;
}

// Wt[r][n][k] = W[r][k][n], bf16
__global__ __launch_bounds__(256) void conv_w_kernel(
    const float* __restrict__ w, unsigned short* __restrict__ wt, int total)
{
    const int t = blockIdx.x * 256 + threadIdx.x;
    if (t >= total) return;
    const int r = t >> 14, rem = t & 16383;
    const int n = rem >> 7, k = rem & 127;
    wt[t] = f2bf(w[(r << 14) + (k << 7) + n]);
}

// ---------------- prep: fused converts + XCD-local bin fill -----------------
// Blocks [0,nbI): inp f32->bf16. [nbI,nbI+nbW): W transpose+convert. Rest:
// bin fill (atomic-append, XCD-local cells). Converts are streaming and ride
// free under the atomic-bound fill.
// binned entry: .x = (rel<<25)|((dst&63)<<19)|src  (needs rel<8, src<2^19)
//               .y = val bits
__global__ __launch_bounds__(256) void prep_kernel(
    const float* __restrict__ x, unsigned short* __restrict__ y, int n8, int nbI,
    const float* __restrict__ w, unsigned short* __restrict__ wtb, int wtot, int nbW,
    const int* __restrict__ src, const int* __restrict__ dst,
    const float* __restrict__ vals, int* __restrict__ bin_cnt,
    int2* __restrict__ binned, int4* __restrict__ spill,
    int* __restrict__ spill_cnt,
    int n_edges, int n_nodes, int nbins, int cap, int spill_max, int fill_gx)
{
    const int bid = blockIdx.x;
    const int tid = threadIdx.x;
    if (bid < nbI) {
        const int i = bid * 256 + tid;
        if (i >= n8) return;
        const float4 a = ((const float4*)x)[i * 2];
        const float4 b = ((const float4*)x)[i * 2 + 1];
        uint4 o;
        o.x = (unsigned)f2bf(a.x) | ((unsigned)f2bf(a.y) << 16);
        o.y = (unsigned)f2bf(a.z) | ((unsigned)f2bf(a.w) << 16);
        o.z = (unsigned)f2bf(b.x) | ((unsigned)f2bf(b.y) << 16);
        o.w = (unsigned)f2bf(b.z) | ((unsigned)f2bf(b.w) << 16);
        ((uint4*)y)[i] = o;
        return;
    }
    if (bid < nbI + nbW) {
        const int t = (bid - nbI) * 256 + tid;
        if (t >= wtot) return;
        const int r = t >> 14, rem = t & 16383;
        const int n = rem >> 7, k = rem & 127;
        wtb[t] = f2bf(w[(r << 14) + (k << 7) + n]);
        return;
    }
    // fill
    int xcd;
    asm volatile("s_getreg_b32 %0, hwreg(HW_REG_XCC_ID)" : "=s"(xcd));
    xcd &= (NXCD - 1);
    const int idx = bid - nbI - nbW;
    const int rel = idx / fill_gx;
    const int e = (idx - rel * fill_gx) * 256 + tid;
    if (e >= n_edges) return;
    const size_t g = (size_t)rel * n_edges + e;
    const int d = dst[g];
    const int s = src[g];
    const int bin = d >> 6;                       // NPB = 64
    const int packed = (rel << 25) | ((d & 63) << 19) | s;
    const int cell = xcd * nbins + bin;
    const int pos = atomicAdd(&bin_cnt[cell * CPAD], 1);
    if (pos < cap) {
        binned[(size_t)cell * cap + pos] =
            make_int2(packed, __float_as_int(vals[g]));
    } else {
        const int sp = atomicAdd(spill_cnt, 1);
        if (sp < spill_max)
            spill[sp] = make_int4(d, (rel << 19) | s, __float_as_int(vals[g]), 0);
    }
}

// ---------------- fused gather + GEMM per bin -------------------------------
// One block per bin (64 nodes). Build LDS-CSR keyed by (rel,lnode) [512
// groups], then per relation: half-wave register-gathers val*inp[src] rows
// (L2-resident table) into a 64x128 bf16 LDS A-tile, MFMA vs Wt[rel],
// f32 accumulate across relations in registers, single coalesced out write.
__global__ __launch_bounds__(256) void bin_gather_gemm(
    const unsigned short* __restrict__ inpb,
    const unsigned short* __restrict__ wt,
    const int2* __restrict__ binned, const int* __restrict__ bin_cnt,
    float* __restrict__ out, int n_nodes, int nbins, int cap, int n_rel)
{
    __shared__ int2 sorted[MAXE];                 // 16 KB
    __shared__ unsigned short A[64 * LDK];        // 17 KB
    __shared__ int lcnt[NGRP], loff[NGRP], lcur[NGRP];   // 6 KB
    __shared__ int cellcnt[NXCD];

    const int bin = blockIdx.x;
    const int tid = threadIdx.x;

    for (int i = tid; i < NGRP; i += 256) lcnt[i] = 0;
    if (tid < NXCD) {
        int c = bin_cnt[(tid * nbins + bin) * CPAD];
        cellcnt[tid] = c > cap ? cap : c;
    }
    __syncthreads();

    // pass 1: histogram by group g = (packed>>19)&511 = rel*64+lnode
    for (int xc = 0; xc < NXCD; ++xc) {
        const int cnt = cellcnt[xc];
        const int2* __restrict__ b = binned + (size_t)(xc * nbins + bin) * cap;
        for (int i = tid; i < cnt; i += 256)
            atomicAdd(&lcnt[(b[i].x >> 19) & (NGRP - 1)], 1);
    }
    __syncthreads();

    // exclusive scan over 512 groups: wave 0, 64 lanes x 8 groups each
    if (tid < 64) {
        const int base = tid * 8;
        int v[8]; int s = 0;
        #pragma unroll
        for (int i = 0; i < 8; ++i) { v[i] = s; s += lcnt[base + i]; }
        int incl = s;
        #pragma unroll
        for (int off = 1; off < 64; off <<= 1) {
            int t = __shfl_up(incl, off, 64);
            if (tid >= off) incl += t;
        }
        const int excl = incl - s;
        #pragma unroll
        for (int i = 0; i < 8; ++i) loff[base + i] = excl + v[i];
    }
    for (int i = tid; i < NGRP; i += 256) lcur[i] = 0;
    __syncthreads();

    // pass 2: place (cells L2-hot after pass 1)
    for (int xc = 0; xc < NXCD; ++xc) {
        const int cnt = cellcnt[xc];
        const int2* __restrict__ b = binned + (size_t)(xc * nbins + bin) * cap;
        for (int i = tid; i < cnt; i += 256) {
            const int2 e = b[i];
            const int g = (e.x >> 19) & (NGRP - 1);
            const int pos = atomicAdd(&lcur[g], 1);
            sorted[loff[g] + pos] = e;
        }
    }
    __syncthreads();

    const int wave = tid >> 6, lane = tid & 63;
    const int m = lane & 15, q = lane >> 4;
    const int hw = tid >> 5, hlane = tid & 31;

    f32x4 acc[4][2];
    #pragma unroll
    for (int mt = 0; mt < 4; ++mt) {
        acc[mt][0] = (f32x4){0.f, 0.f, 0.f, 0.f};
        acc[mt][1] = (f32x4){0.f, 0.f, 0.f, 0.f};
    }

    for (int r = 0; r < n_rel; ++r) {
        // gather: half-wave hw owns local nodes hw*8..hw*8+7
        #pragma unroll
        for (int k = 0; k < 8; ++k) {
            const int ln = hw * 8 + k;
            const int g = r * 64 + ln;
            const int base = loff[g], cnt = lcnt[g];
            float4 a4 = make_float4(0.f, 0.f, 0.f, 0.f);
            int j = 0;
            for (; j + 4 <= cnt; j += 4) {
                const int2 r0 = sorted[base + j],     r1 = sorted[base + j + 1];
                const int2 r2 = sorted[base + j + 2], r3 = sorted[base + j + 3];
                const uint2 h0 = ((const uint2*)(inpb + (size_t)(r0.x & 0x7ffff) * IN))[hlane];
                const uint2 h1 = ((const uint2*)(inpb + (size_t)(r1.x & 0x7ffff) * IN))[hlane];
                const uint2 h2 = ((const uint2*)(inpb + (size_t)(r2.x & 0x7ffff) * IN))[hlane];
                const uint2 h3 = ((const uint2*)(inpb + (size_t)(r3.x & 0x7ffff) * IN))[hlane];
                const float v0 = __int_as_float(r0.y), v1 = __int_as_float(r1.y);
                const float v2 = __int_as_float(r2.y), v3 = __int_as_float(r3.y);
                a4.x += v0*bflo(h0.x) + v1*bflo(h1.x) + v2*bflo(h2.x) + v3*bflo(h3.x);
                a4.y += v0*bfhi(h0.x) + v1*bfhi(h1.x) + v2*bfhi(h2.x) + v3*bfhi(h3.x);
                a4.z += v0*bflo(h0.y) + v1*bflo(h1.y) + v2*bflo(h2.y) + v3*bflo(h3.y);
                a4.w += v0*bfhi(h0.y) + v1*bfhi(h1.y) + v2*bfhi(h2.y) + v3*bfhi(h3.y);
            }
            for (; j < cnt; ++j) {
                const int2 r0 = sorted[base + j];
                const float v = __int_as_float(r0.y);
                const uint2 hv = ((const uint2*)(inpb + (size_t)(r0.x & 0x7ffff) * IN))[hlane];
                a4.x += v * bflo(hv.x); a4.y += v * bfhi(hv.x);
                a4.z += v * bflo(hv.y); a4.w += v * bfhi(hv.y);
            }
            uint2 o;
            o.x = (unsigned)f2bf(a4.x) | ((unsigned)f2bf(a4.y) << 16);
            o.y = (unsigned)f2bf(a4.z) | ((unsigned)f2bf(a4.w) << 16);
            *(uint2*)&A[ln * LDK + hlane * 4] = o;
        }
        __syncthreads();    // A-tile ready

        const unsigned short* wtr = wt + ((size_t)r * OUT + wave * 32) * IN;
        bf16x8 bfrag[2][4];
        #pragma unroll
        for (int nt = 0; nt < 2; ++nt)
            #pragma unroll
            for (int ks = 0; ks < 4; ++ks)
                bfrag[nt][ks] = *(const bf16x8*)(
                    wtr + (size_t)(nt * 16 + m) * IN + ks * 32 + q * 8);

        #pragma unroll
        for (int ks = 0; ks < 4; ++ks) {
            bf16x8 a[4];
            #pragma unroll
            for (int mt = 0; mt < 4; ++mt)
                a[mt] = *(const bf16x8*)&A[(mt * 16 + m) * LDK + ks * 32 + q * 8];
            #pragma unroll
            for (int mt = 0; mt < 4; ++mt) {
                acc[mt][0] = __builtin_amdgcn_mfma_f32_16x16x32_bf16(
                    a[mt], bfrag[0][ks], acc[mt][0], 0, 0, 0);
                acc[mt][1] = __builtin_amdgcn_mfma_f32_16x16x32_bf16(
                    a[mt], bfrag[1][ks], acc[mt][1], 0, 0, 0);
            }
        }
        __syncthreads();    // before next rel overwrites A
    }

    // epilogue: lane holds rows q*4+0..3 of each 16-row M-tile, col nt*16+m
    const int row0 = bin * NPB;
    #pragma unroll
    for (int mt = 0; mt < 4; ++mt) {
        #pragma unroll
        for (int rg = 0; rg < 4; ++rg) {
            const int row = row0 + mt * 16 + q * 4 + rg;
            if (row < n_nodes) {
                float* op = out + (size_t)row * OUT + wave * 32 + m;
                op[0]  = acc[mt][0][rg];
                op[16] = acc[mt][1][rg];
            }
        }
    }
}

// ---------------- spill cleanup: out[d] += val * (inp[src] @ W[rel]) --------
__global__ __launch_bounds__(256) void spill_w_kernel(
    const unsigned short* __restrict__ inpb,
    const unsigned short* __restrict__ wt,
    const int4* __restrict__ spill, const int* __restrict__ spill_cnt,
    float* __restrict__ out, int spill_max)
{
    int n = *spill_cnt;
    if (n > spill_max) n = spill_max;
    const int w = (blockIdx.x * 256 + threadIdx.x) >> 6;
    const int lane = threadIdx.x & 63;
    const int nw = gridDim.x * 4;
    for (int i = w; i < n; i += nw) {
        const int4 s = spill[i];
        const int d = s.x;
        const int rel = s.y >> 19, srcrow = s.y & 0x7ffff;
        const float v = __int_as_float(s.z);
        const unsigned short* irow = inpb + (size_t)srcrow * IN;
        #pragma unroll
        for (int cc = 0; cc < 2; ++cc) {
            const int col = lane * 2 + cc;
            const unsigned short* wrow = wt + ((size_t)rel * OUT + col) * IN;
            float acc = 0.f;
            for (int k8 = 0; k8 < IN; k8 += 8) {
                const uint4 iw = *(const uint4*)(irow + k8);
                const uint4 ww = *(const uint4*)(wrow + k8);
                acc += bflo(iw.x)*bflo(ww.x) + bfhi(iw.x)*bfhi(ww.x)
                     + bflo(iw.y)*bflo(ww.y) + bfhi(iw.y)*bfhi(ww.y)
                     + bflo(iw.z)*bflo(ww.z) + bfhi(iw.z)*bfhi(ww.z)
                     + bflo(iw.w)*bflo(ww.w) + bfhi(iw.w)*bfhi(ww.w);
            }
            __hip_atomic_fetch_add(out + (size_t)d * OUT + col, v * acc,
                                   __ATOMIC_RELAXED, __HIP_MEMORY_SCOPE_AGENT);
        }
    }
}

// ================= legacy fallback machinery (h-based) ======================
__global__ __launch_bounds__(256) void mfma_gemm(
    const unsigned short* __restrict__ inpb,
    const unsigned short* __restrict__ wt,
    unsigned short* __restrict__ h, int rel_base, int n_nodes)
{
    __shared__ unsigned short As[128 * LDK];

    const int rel = rel_base + blockIdx.y;
    const int row0 = blockIdx.x * 128;
    const int tid = threadIdx.x;
    const int wave = tid >> 6, lane = tid & 63;
    const int m = lane & 15, q = lane >> 4;

    {
        const int r = tid >> 1;
        const int half = (tid & 1) * 64;
        const int grow = row0 + r;
        const uint4* gp = (const uint4*)(inpb + (size_t)grow * IN + half);
        uint4* lp = (uint4*)&As[r * LDK + half];
        #pragma unroll
        for (int i = 0; i < 8; ++i) {
            uint4 v = make_uint4(0u, 0u, 0u, 0u);
            if (grow < n_nodes) v = gp[i];
            lp[i] = v;
        }
    }

    bf16x8 bfrag[2][4];
    {
        const unsigned short* wtr = wt + ((size_t)rel * OUT + wave * 32) * IN;
        #pragma unroll
        for (int nt = 0; nt < 2; ++nt)
            #pragma unroll
            for (int ks = 0; ks < 4; ++ks)
                bfrag[nt][ks] = *(const bf16x8*)(
                    wtr + (size_t)(nt * 16 + m) * IN + ks * 32 + q * 8);
    }

    __syncthreads();

    f32x4 acc[8][2];
    #pragma unroll
    for (int mt = 0; mt < 8; ++mt)
        #pragma unroll
        for (int nt = 0; nt < 2; ++nt)
            acc[mt][nt] = (f32x4){0.f, 0.f, 0.f, 0.f};

    #pragma unroll
    for (int ks = 0; ks < 4; ++ks) {
        bf16x8 a[8];
        #pragma unroll
        for (int mt = 0; mt < 8; ++mt)
            a[mt] = *(const bf16x8*)&As[(mt * 16 + m) * LDK + ks * 32 + q * 8];
        #pragma unroll
        for (int mt = 0; mt < 8; ++mt) {
            acc[mt][0] = __builtin_amdgcn_mfma_f32_16x16x32_bf16(
                a[mt], bfrag[0][ks], acc[mt][0], 0, 0, 0);
            acc[mt][1] = __builtin_amdgcn_mfma_f32_16x16x32_bf16(
                a[mt], bfrag[1][ks], acc[mt][1], 0, 0, 0);
        }
    }

    unsigned short* hrel = h + (size_t)blockIdx.y * n_nodes * OUT;
    #pragma unroll
    for (int mt = 0; mt < 8; ++mt) {
        #pragma unroll
        for (int rg = 0; rg < 4; ++rg) {
            const int row = row0 + mt * 16 + q * 4 + rg;
            if (row < n_nodes) {
                unsigned short* hp = hrel + (size_t)row * OUT + wave * 32 + m;
                hp[0]  = f2bf(acc[mt][0][rg]);
                hp[16] = f2bf(acc[mt][1][rg]);
            }
        }
    }
}

__global__ __launch_bounds__(256) void fill_kernel(
    const int* __restrict__ src, const int* __restrict__ dst,
    const float* __restrict__ vals, int* __restrict__ counts,
    int2* __restrict__ bucket, int4* __restrict__ spill,
    int* __restrict__ spill_cnt, int n_edges, int n_nodes,
    int cap, int spill_max)
{
    const int e = blockIdx.x * 256 + threadIdx.x;
    if (e >= n_edges) return;
    const size_t g = (size_t)blockIdx.y * n_edges + e;
    const int d = dst[g];
    const int enc = blockIdx.y * n_nodes + src[g];
    const int pos = atomicAdd(&counts[d], 1);
    if (pos < cap) {
        bucket[(size_t)d * cap + pos] = make_int2(enc, __float_as_int(vals[g]));
    } else {
        const int sp = atomicAdd(spill_cnt, 1);
        if (sp < spill_max)
            spill[sp] = make_int4(d, enc, __float_as_int(vals[g]), 0);
    }
}

__global__ __launch_bounds__(256) void gather_kernel(
    const unsigned short* __restrict__ h, const int2* __restrict__ bucket,
    const int* __restrict__ counts, float* __restrict__ out,
    int n_nodes, int cap, int accum)
{
    const int node = blockIdx.x * 8 + (threadIdx.x >> 5);
    const int lane = threadIdx.x & 31;
    if (node >= n_nodes) return;
    int cnt = counts[node];
    if (cnt > cap) cnt = cap;
    const int2* __restrict__ b = bucket + (size_t)node * cap;
    float4* __restrict__ op = (float4*)(out + (size_t)node * OUT);

    float4 acc = accum ? op[lane] : make_float4(0.f, 0.f, 0.f, 0.f);
    int j = 0;
    for (; j + 4 <= cnt; j += 4) {
        const int2 r0 = b[j], r1 = b[j + 1], r2 = b[j + 2], r3 = b[j + 3];
        const uint2 h0 = ((const uint2*)(h + (size_t)r0.x * OUT))[lane];
        const uint2 h1 = ((const uint2*)(h + (size_t)r1.x * OUT))[lane];
        const uint2 h2 = ((const uint2*)(h + (size_t)r2.x * OUT))[lane];
        const uint2 h3 = ((const uint2*)(h + (size_t)r3.x * OUT))[lane];
        const float v0 = __int_as_float(r0.y), v1 = __int_as_float(r1.y);
        const float v2 = __int_as_float(r2.y), v3 = __int_as_float(r3.y);
        acc.x += v0*bflo(h0.x) + v1*bflo(h1.x) + v2*bflo(h2.x) + v3*bflo(h3.x);
        acc.y += v0*bfhi(h0.x) + v1*bfhi(h1.x) + v2*bfhi(h2.x) + v3*bfhi(h3.x);
        acc.z += v0*bflo(h0.y) + v1*bflo(h1.y) + v2*bflo(h2.y) + v3*bflo(h3.y);
        acc.w += v0*bfhi(h0.y) + v1*bfhi(h1.y) + v2*bfhi(h2.y) + v3*bfhi(h3.y);
    }
    for (; j < cnt; ++j) {
        const int2 r0 = b[j];
        const float v = __int_as_float(r0.y);
        const uint2 hv = ((const uint2*)(h + (size_t)r0.x * OUT))[lane];
        acc.x += v * bflo(hv.x); acc.y += v * bfhi(hv.x);
        acc.z += v * bflo(hv.y); acc.w += v * bfhi(hv.y);
    }
    op[lane] = acc;
}

__global__ __launch_bounds__(256) void spill_kernel(
    const unsigned short* __restrict__ h, const int4* __restrict__ spill,
    const int* __restrict__ spill_cnt, float* __restrict__ out, int spill_max)
{
    int n = *spill_cnt;
    if (n > spill_max) n = spill_max;
    const int w = (blockIdx.x * 256 + threadIdx.x) >> 6;
    const int lane = threadIdx.x & 63;
    const int nw = gridDim.x * 4;
    for (int i = w; i < n; i += nw) {
        const int4 s = spill[i];
        const float v = __int_as_float(s.z);
        const unsigned int u = ((const unsigned int*)(h + (size_t)s.y * OUT))[lane];
        float* __restrict__ orow = out + (size_t)s.x * OUT;
        __hip_atomic_fetch_add(orow + lane * 2,     v * bflo(u),
                               __ATOMIC_RELAXED, __HIP_MEMORY_SCOPE_AGENT);
        __hip_atomic_fetch_add(orow + lane * 2 + 1, v * bfhi(u),
                               __ATOMIC_RELAXED, __HIP_MEMORY_SCOPE_AGENT);
    }
}

__global__ __launch_bounds__(256) void scatter_kernel(
    const unsigned short* __restrict__ h, const int* __restrict__ src,
    const int* __restrict__ dst, const float* __restrict__ vals,
    float* __restrict__ out, int n_edges)
{
    const int e = blockIdx.x * 8 + (threadIdx.x >> 5);
    if (e >= n_edges) return;
    const int lane = threadIdx.x & 31;
    const int s = src[e];
    const int d = dst[e];
    const float v = vals[e];
    const unsigned int* __restrict__ hrow =
        (const unsigned int*)(h + (size_t)s * OUT);
    float* __restrict__ orow = out + (size_t)d * OUT;
    #pragma unroll
    for (int kk = 0; kk < 2; ++kk) {
        const int jj = lane + kk * 32;
        const unsigned int u = hrow[jj];
        __hip_atomic_fetch_add(orow + jj * 2,     v * bflo(u),
                               __ATOMIC_RELAXED, __HIP_MEMORY_SCOPE_AGENT);
        __hip_atomic_fetch_add(orow + jj * 2 + 1, v * bfhi(u),
                               __ATOMIC_RELAXED, __HIP_MEMORY_SCOPE_AGENT);
    }
}

extern "C" void kernel_launch(void* const* d_in, const int* in_sizes, int n_in,
                              void* d_out, int out_size, void* d_ws, size_t ws_size,
                              hipStream_t stream) {
    const float* inp     = (const float*)d_in[0];
    const int*   src     = (const int*)  d_in[1];
    const int*   dst     = (const int*)  d_in[2];
    const float* vals    = (const float*)d_in[3];
    const float* weights = (const float*)d_in[4];
    float* out = (float*)d_out;

    const int n_nodes = in_sizes[0] / IN;            // 50000
    const int n_rel   = in_sizes[4] / (IN * OUT);    // 8
    const int n_edges = in_sizes[1] / n_rel;         // 100000

    auto align_up = [](size_t x) { return (x + 255) & ~(size_t)255; };
    const int SPILL_MAX = 65536;
    const size_t sz_inpb   = align_up((size_t)n_nodes * IN * 2);
    const size_t sz_wt     = align_up((size_t)n_rel * IN * OUT * 2);
    const size_t sz_spill  = align_up((size_t)SPILL_MAX * 16);

    const int conv_n8 = n_nodes * IN / 8;
    const int wt_tot  = n_rel * IN * OUT;
    const int gemm_gx = (n_nodes + 127) / 128;
    const int gath_gx = (n_nodes + 7) / 8;
    const int fill_gx = (n_edges + 255) / 256;
    const int nbins   = (n_nodes + NPB - 1) / NPB;

    // ---- primary path: input-space segsum + fused per-bin MFMA ----
    if (n_rel <= 8 && n_nodes < (1 << 19)) {
        const size_t sz_bcnt = align_up(((size_t)NXCD * nbins * CPAD + CPAD) * 4);
        int cap = 0;
        const int caps[] = {256, 192};
        for (int c : caps) {
            const size_t sz_binned = align_up((size_t)NXCD * nbins * c * 8);
            if (sz_inpb + sz_wt + sz_bcnt + sz_spill + sz_binned <= ws_size) {
                cap = c; break;
            }
        }
        if (cap > 0) {
            const size_t sz_binned = align_up((size_t)NXCD * nbins * cap * 8);
            char* p = (char*)d_ws;
            unsigned short* inpb = (unsigned short*)p;  p += sz_inpb;
            unsigned short* wtb  = (unsigned short*)p;  p += sz_wt;
            int*   bin_cnt = (int*)p;   p += sz_bcnt;
            int4*  spill   = (int4*)p;  p += sz_spill;
            int2*  binned  = (int2*)p;  p += sz_binned;
            int*   spill_cnt = bin_cnt + (size_t)NXCD * nbins * CPAD;

            const int nbI = (conv_n8 + 255) / 256;
            const int nbW = (wt_tot + 255) / 256;
            const int nF  = fill_gx * n_rel;

            hipMemsetAsync(bin_cnt, 0,
                           ((size_t)NXCD * nbins * CPAD + CPAD) * 4, stream);
            prep_kernel<<<nbI + nbW + nF, 256, 0, stream>>>(
                inp, inpb, conv_n8, nbI, weights, wtb, wt_tot, nbW,
                src, dst, vals, bin_cnt, binned, spill, spill_cnt,
                n_edges, n_nodes, nbins, cap, SPILL_MAX, fill_gx);
            bin_gather_gemm<<<nbins, 256, 0, stream>>>(
                inpb, wtb, binned, bin_cnt, out, n_nodes, nbins, cap, n_rel);
            spill_w_kernel<<<128, 256, 0, stream>>>(
                inpb, wtb, spill, spill_cnt, out, SPILL_MAX);
            return;
        }
    }

    const size_t sz_counts = align_up((size_t)(n_nodes + 1) * 4);
    const size_t fixed = sz_inpb + sz_wt + sz_counts + sz_spill;

    // ---- legacy full path: per-node buckets + h GEMM + gather ----
    {
        const size_t sz_h = (size_t)n_rel * n_nodes * OUT * 2;
        int cap = 0;
        const int caps[] = {64, 48, 32, 24, 20};
        for (int c : caps) {
            if (fixed + sz_h + align_up((size_t)n_nodes * c * 8) <= ws_size) {
                cap = c; break;
            }
        }
        if (cap > 0) {
            char* p = (char*)d_ws;
            unsigned short* inpb = (unsigned short*)p;  p += sz_inpb;
            unsigned short* wtb  = (unsigned short*)p;  p += sz_wt;
            int*   counts = (int*)p;    p += sz_counts;
            int4*  spill  = (int4*)p;   p += sz_spill;
            unsigned short* h = (unsigned short*)p;     p += sz_h;
            int2*  bucket = (int2*)p;
            int*   spill_cnt = counts + n_nodes;

            conv_inp_kernel<<<(conv_n8 + 255) / 256, 256, 0, stream>>>(
                inp, inpb, conv_n8);
            conv_w_kernel<<<(wt_tot + 255) / 256, 256, 0, stream>>>(
                weights, wtb, wt_tot);
            hipMemsetAsync(counts, 0, (size_t)(n_nodes + 1) * 4, stream);
            dim3 fg(fill_gx, n_rel);
            fill_kernel<<<fg, 256, 0, stream>>>(src, dst, vals, counts, bucket,
                                                spill, spill_cnt, n_edges,
                                                n_nodes, cap, SPILL_MAX);
            dim3 gg(gemm_gx, n_rel);
            mfma_gemm<<<gg, 256, 0, stream>>>(inpb, wtb, h, 0, n_nodes);
            gather_kernel<<<gath_gx, 256, 0, stream>>>(h, bucket, counts, out,
                                                       n_nodes, cap, 0);
            spill_kernel<<<128, 256, 0, stream>>>(h, spill, spill_cnt, out,
                                                  SPILL_MAX);
            return;
        }
    }

    // ---- last resort: per-relation gemm + atomic scatter ----
    {
        char* p = (char*)d_ws;
        unsigned short* inpb = (unsigned short*)p;  p += sz_inpb;
        unsigned short* wtb  = (unsigned short*)p;  p += sz_wt;
        unsigned short* h = (unsigned short*)p;

        conv_inp_kernel<<<(conv_n8 + 255) / 256, 256, 0, stream>>>(
            inp, inpb, conv_n8);
        conv_w_kernel<<<(wt_tot + 255) / 256, 256, 0, stream>>>(
            weights, wtb, wt_tot);
        hipMemsetAsync(out, 0, (size_t)n_nodes * OUT * 4, stream);
        const int sgx = (n_edges + 7) / 8;
        for (int r = 0; r < n_rel; ++r) {
            const size_t eoff = (size_t)r * n_edges;
            dim3 gg(gemm_gx, 1);
            mfma_gemm<<<gg, 256, 0, stream>>>(inpb, wtb, h, r, n_nodes);
            scatter_kernel<<<sgx, 256, 0, stream>>>(h, src + eoff, dst + eoff,
                                                    vals + eoff, out, n_edges);
        }
    }
}